// Round 9
// baseline (110.961 us; speedup 1.0000x reference)
//
#include <hip/hip_runtime.h>
#include <stdint.h>

#define SGRID 128
#define CAP 4096   // per-offset pair capacity (expect ~2400 at this density)

typedef _Float16 f16;
typedef f16 f16x8 __attribute__((ext_vector_type(8)));
typedef float f32x4 __attribute__((ext_vector_type(4)));

static __device__ __forceinline__ f32x4 mfma16(uint4 a, uint4 b, f32x4 c) {
    union { uint4 u; f16x8 v; } ua, ub;
    ua.u = a; ub.u = b;
    return __builtin_amdgcn_mfma_f32_16x16x32_f16(ua.v, ub.v, c, 0, 0, 0);
}

// split 8 f32 -> f16 hi + f16 lo (packed uint4 fragments)
static __device__ __forceinline__ void split8(const float* v, uint4& hu, uint4& lu) {
    union { f16 h[8]; uint4 u; } hv, lv;
    #pragma unroll
    for (int j = 0; j < 8; ++j) {
        f16 h = (f16)v[j];
        hv.h[j] = h;
        lv.h[j] = (f16)(v[j] - (float)h);
    }
    hu = hv.u; lu = lv.u;
}

// ---- shared center-tap body: one wave = 32 points x 64 cout, W slot 13 ----
static __device__ __forceinline__ void center_body(
    const float* __restrict__ A, const f16* __restrict__ Wp,
    float* __restrict__ O, int N, int gw, int lane)
{
    const int r = lane & 15, lq = lane >> 4;
    const int p0 = gw * 32;

    const uint4* wb = (const uint4*)Wp + 13 * 512 + lane;
    uint4 b[2][4];
    #pragma unroll
    for (int ct = 0; ct < 4; ++ct)
        #pragma unroll
        for (int ks = 0; ks < 2; ++ks)
            b[ks][ct] = wb[(ct * 2 + ks) * 64];

    uint4 ah[2][2], al[2][2];
    #pragma unroll
    for (int rt = 0; rt < 2; ++rt) {
        int row = p0 + rt * 16 + r;
        #pragma unroll
        for (int ks = 0; ks < 2; ++ks) {
            float v[8];
            if (row < N) {
                float4 v0 = *(const float4*)(A + (size_t)row * 64 + ks * 32 + lq * 8);
                float4 v1 = *(const float4*)(A + (size_t)row * 64 + ks * 32 + lq * 8 + 4);
                v[0]=v0.x; v[1]=v0.y; v[2]=v0.z; v[3]=v0.w;
                v[4]=v1.x; v[5]=v1.y; v[6]=v1.z; v[7]=v1.w;
            } else {
                #pragma unroll
                for (int j = 0; j < 8; ++j) v[j] = 0.f;
            }
            split8(v, ah[rt][ks], al[rt][ks]);
        }
    }

    f32x4 acc[2][4];
    #pragma unroll
    for (int i = 0; i < 2; ++i)
        #pragma unroll
        for (int j = 0; j < 4; ++j) acc[i][j] = (f32x4){0.f, 0.f, 0.f, 0.f};

    #pragma unroll
    for (int ks = 0; ks < 2; ++ks)
        #pragma unroll
        for (int rt = 0; rt < 2; ++rt)
            #pragma unroll
            for (int ct = 0; ct < 4; ++ct) {
                acc[rt][ct] = mfma16(ah[rt][ks], b[ks][ct], acc[rt][ct]);
                acc[rt][ct] = mfma16(al[rt][ks], b[ks][ct], acc[rt][ct]);
            }

    #pragma unroll
    for (int rt = 0; rt < 2; ++rt)
        #pragma unroll
        for (int j = 0; j < 4; ++j) {
            int row = p0 + rt * 16 + lq * 4 + j;
            if (row < N) {
                #pragma unroll
                for (int ct = 0; ct < 4; ++ct)
                    O[(size_t)row * 64 + ct * 16 + r] = acc[rt][ct][j];
            }
        }
}

// ---------------- K1: clear bitmap + counters ----------------
__global__ void clear_meta(uint4* __restrict__ bitmap4, int nwords4, int* __restrict__ cnt) {
    int i = blockIdx.x * 256 + threadIdx.x;
    if (i < nwords4) bitmap4[i] = (uint4){0, 0, 0, 0};
    if (blockIdx.x == 0 && threadIdx.x < 26) cnt[threadIdx.x * 16] = 0;
}

// ---------------- K2: scatter table/bitmap + prep W frags (mixed grid) ----------------
__global__ void __launch_bounds__(256) scatter_prep(
    const int* __restrict__ coords, int* __restrict__ table,
    unsigned* __restrict__ bitmap, int N, int scatB,
    const float* __restrict__ W1, const float* __restrict__ W2,
    f16* __restrict__ Wp1, f16* __restrict__ Wp2)
{
    const int tid = threadIdx.x;
    if (blockIdx.x < scatB) {
        int i = blockIdx.x * 256 + tid;
        if (i < N) {
            int4 c = ((const int4*)coords)[i];
            int key = ((c.x * SGRID + c.y) * SGRID + c.z) * SGRID + c.w;
            table[key] = i;
            atomicOr(&bitmap[key >> 5], 1u << (key & 31));
        }
        return;
    }
    int idx = (blockIdx.x - scatB) * 256 + tid;   // < 27648
    const int half = 27 * 512;
    const float* W = (idx < half) ? W1 : W2;
    f16* Wp = (idx < half) ? Wp1 : Wp2;
    int id = (idx < half) ? idx : idx - half;
    int lane = id & 63;
    int ks = (id >> 6) & 1;
    int ct = (id >> 7) & 3;
    int o  = id >> 9;
    int co  = ct * 16 + (lane & 15);
    int ci0 = ks * 32 + (lane >> 4) * 8;
    union { f16 h[8]; uint4 u; } hv;
    #pragma unroll
    for (int j = 0; j < 8; ++j)
        hv.h[j] = (f16)W[((size_t)o * 64 + ci0 + j) * 64 + co];
    ((uint4*)Wp)[id] = hv.u;
}

// ---------------- K3: FLAT pair build (1 probe/thread) + center tap layer 1 ----------------
__global__ void __launch_bounds__(256) build_center(
    const int* __restrict__ coords, const int* __restrict__ table,
    const unsigned* __restrict__ bitmap,
    int* __restrict__ pin, int* __restrict__ pout, int* __restrict__ cnt,
    int N, int chunks,
    const float* __restrict__ F, const f16* __restrict__ Wp, float* __restrict__ H)
{
    const int tid = threadIdx.x;
    const int bid = blockIdx.x;
    const int buildB = chunks * 26;

    if (bid >= buildB) {               // center-tap blocks
        int gw = ((bid - buildB) * 256 + tid) >> 6;
        if (gw < (N + 31) >> 5)
            center_body(F, Wp, H, N, gw, tid & 63);
        return;
    }

    // one probe per thread: slot = which of 26 offsets, chunk = which 256 points
    const int slot  = bid / chunks;
    const int chunk = bid - slot * chunks;
    const int n     = chunk * 256 + tid;
    const int lane  = tid & 63, wave = tid >> 6;

    int nb = -1;
    if (n < N) {
        int4 c = ((const int4*)coords)[n];
        int o = slot < 13 ? slot : slot + 1;
        int dx = o / 9 - 1, dy = (o / 3) % 3 - 1, dz = o % 3 - 1;
        int qx = c.y + dx, qy = c.z + dy, qz = c.w + dz;
        if ((unsigned)qx < SGRID && (unsigned)qy < SGRID && (unsigned)qz < SGRID) {
            int qkey = ((c.x * SGRID + qx) * SGRID + qy) * SGRID + qz;
            if ((bitmap[qkey >> 5] >> (qkey & 31)) & 1u)
                nb = table[qkey];
        }
    }

    __shared__ int swc[4];
    unsigned long long bal = __ballot(nb >= 0);
    if (lane == 0) swc[wave] = (int)__popcll(bal);
    __syncthreads();
    if (tid == 0) {
        int t0 = swc[0], t1 = swc[1], t2 = swc[2], t3 = swc[3];
        int tot = t0 + t1 + t2 + t3;
        int base = tot ? atomicAdd(&cnt[slot * 16], tot) : 0;
        swc[0] = base;
        swc[1] = base + t0;
        swc[2] = base + t0 + t1;
        swc[3] = base + t0 + t1 + t2;
    }
    __syncthreads();
    if (nb >= 0) {
        int pos = swc[wave] + (int)__popcll(bal & ((1ull << lane) - 1ull));
        if (pos < CAP) {
            pin[slot * CAP + pos]  = nb;
            pout[slot * CAP + pos] = n;
        }
    }
}

// ---------------- K5: standalone center (layer 2) ----------------
__global__ void __launch_bounds__(256) conv_center(
    const float* __restrict__ A, const f16* __restrict__ Wp,
    float* __restrict__ O, int N)
{
    int gw = (blockIdx.x * 256 + threadIdx.x) >> 6;
    if (gw < (N + 31) >> 5)
        center_body(A, Wp, O, N, gw, threadIdx.x & 63);
}

// ---------------- K4/K6: sparse taps, 16-pair chunks, cout halves ----------------
__global__ void __launch_bounds__(256) conv_sparse(
    const float* __restrict__ A, const f16* __restrict__ Wp,
    const int* __restrict__ pin, const int* __restrict__ pout,
    const int* __restrict__ cnt, float* __restrict__ O)
{
    int w = (blockIdx.x * 256 + threadIdx.x) >> 6;
    if (w >= 26 * 512) return;
    int slot  = w >> 9;                  // 256 chunks x 2 ch-halves per slot
    int rem   = w & 511;
    int chunk = rem >> 1;
    int ch    = rem & 1;
    int cn = cnt[slot * 16]; if (cn > CAP) cn = CAP;
    int i0 = chunk * 16;
    if (i0 >= cn) return;
    int o = slot < 13 ? slot : slot + 1;
    const int lane = threadIdx.x & 63, r = lane & 15, lq = lane >> 4;

    const uint4* wb = (const uint4*)Wp + (size_t)o * 512 + lane;
    uint4 b[2][2];   // [ct][ks], couts (ch*2+ct)*16..
    #pragma unroll
    for (int ct = 0; ct < 2; ++ct)
        #pragma unroll
        for (int ks = 0; ks < 2; ++ks)
            b[ct][ks] = wb[((ch * 2 + ct) * 2 + ks) * 64];

    int p = i0 + r;
    int in = (p < cn) ? pin[slot * CAP + p] : -1;
    uint4 ah[2], al[2];
    #pragma unroll
    for (int ks = 0; ks < 2; ++ks) {
        float v[8];
        if (in >= 0) {
            float4 v0 = *(const float4*)(A + (size_t)in * 64 + ks * 32 + lq * 8);
            float4 v1 = *(const float4*)(A + (size_t)in * 64 + ks * 32 + lq * 8 + 4);
            v[0]=v0.x; v[1]=v0.y; v[2]=v0.z; v[3]=v0.w;
            v[4]=v1.x; v[5]=v1.y; v[6]=v1.z; v[7]=v1.w;
        } else {
            #pragma unroll
            for (int j = 0; j < 8; ++j) v[j] = 0.f;
        }
        split8(v, ah[ks], al[ks]);
    }

    f32x4 acc[2];
    acc[0] = (f32x4){0.f, 0.f, 0.f, 0.f};
    acc[1] = (f32x4){0.f, 0.f, 0.f, 0.f};
    #pragma unroll
    for (int ks = 0; ks < 2; ++ks)
        #pragma unroll
        for (int ct = 0; ct < 2; ++ct) {
            acc[ct] = mfma16(ah[ks], b[ct][ks], acc[ct]);
            acc[ct] = mfma16(al[ks], b[ct][ks], acc[ct]);
        }

    #pragma unroll
    for (int j = 0; j < 4; ++j) {
        int pr = i0 + lq * 4 + j;
        if (pr < cn) {
            int oidx = pout[slot * CAP + pr];
            #pragma unroll
            for (int ct = 0; ct < 2; ++ct)
                atomicAdd(&O[(size_t)oidx * 64 + (ch * 2 + ct) * 16 + r], acc[ct][j]);
        }
    }
}

extern "C" void kernel_launch(void* const* d_in, const int* in_sizes, int n_in,
                              void* d_out, int out_size, void* d_ws, size_t ws_size,
                              hipStream_t stream) {
    const float* feats  = (const float*)d_in[0];
    const int*   coords = (const int*)d_in[1];
    const float* W1     = (const float*)d_in[2];
    const float* W2     = (const float*)d_in[3];
    float* out = (float*)d_out;

    const int N = in_sizes[0] / 64;
    const size_t nvox = 2ull * SGRID * SGRID * SGRID;   // B * S^3

    char* p = (char*)d_ws;
    int*      table  = (int*)p;      p += nvox * 4;          // no init needed (bitmap-guarded)
    unsigned* bitmap = (unsigned*)p; p += (nvox / 32) * 4;   // 524 KB
    int*      cnt    = (int*)p;      p += 26 * 16 * 4;       // padded, one per cacheline
    int*      pin    = (int*)p;      p += 26ull * CAP * 4;
    int*      pout   = (int*)p;      p += 26ull * CAP * 4;
    float*    H      = (float*)p;    p += (size_t)N * 64 * 4;
    f16*      Wp1    = (f16*)p;      p += 27ull * 4096 * 2;
    f16*      Wp2    = (f16*)p;      p += 27ull * 4096 * 2;

    const int bm4     = (int)(nvox / 32 / 4);            // 32768
    const int scatB   = (N + 255) / 256;                 // 391
    const int chunks  = scatB;                           // probe chunks per slot
    const int ngroups = (N + 31) / 32;
    const int centerB = (ngroups + 3) / 4;               // 1 wave per group, 4/block
    const int sparseB = 26 * 512 / 4;                    // 3328 blocks

    clear_meta<<<(bm4 + 255) / 256, 256, 0, stream>>>((uint4*)bitmap, bm4, cnt);
    scatter_prep<<<scatB + 108, 256, 0, stream>>>(coords, table, bitmap, N, scatB,
                                                  W1, W2, Wp1, Wp2);
    build_center<<<chunks * 26 + centerB, 256, 0, stream>>>(coords, table, bitmap,
                                                            pin, pout, cnt, N, chunks,
                                                            feats, Wp1, H);
    conv_sparse<<<sparseB, 256, 0, stream>>>(feats, Wp1, pin, pout, cnt, H);
    conv_center<<<centerB, 256, 0, stream>>>(H, Wp2, out, N);
    conv_sparse<<<sparseB, 256, 0, stream>>>(H, Wp2, pin, pout, cnt, out);
}

// Round 10
// 102.317 us; speedup vs baseline: 1.0845x; 1.0845x over previous
//
#include <hip/hip_runtime.h>
#include <stdint.h>

#define SGRID 128
#define CAP 4096   // per-offset pair capacity (expect ~2400 at this density)

typedef _Float16 f16;
typedef f16 f16x8 __attribute__((ext_vector_type(8)));
typedef float f32x4 __attribute__((ext_vector_type(4)));

static __device__ __forceinline__ f32x4 mfma16(uint4 a, uint4 b, f32x4 c) {
    union { uint4 u; f16x8 v; } ua, ub;
    ua.u = a; ub.u = b;
    return __builtin_amdgcn_mfma_f32_16x16x32_f16(ua.v, ub.v, c, 0, 0, 0);
}

// split 8 f32 -> f16 hi + f16 lo (packed uint4 fragments)
static __device__ __forceinline__ void split8(const float* v, uint4& hu, uint4& lu) {
    union { f16 h[8]; uint4 u; } hv, lv;
    #pragma unroll
    for (int j = 0; j < 8; ++j) {
        f16 h = (f16)v[j];
        hv.h[j] = h;
        lv.h[j] = (f16)(v[j] - (float)h);
    }
    hu = hv.u; lu = lv.u;
}

// ---- shared center-tap body: one wave = 32 points x 64 cout, W slot 13 ----
static __device__ __forceinline__ void center_body(
    const float* __restrict__ A, const f16* __restrict__ Wp,
    float* __restrict__ O, int N, int gw, int lane)
{
    const int r = lane & 15, lq = lane >> 4;
    const int p0 = gw * 32;

    const uint4* wb = (const uint4*)Wp + 13 * 512 + lane;
    uint4 b[2][4];
    #pragma unroll
    for (int ct = 0; ct < 4; ++ct)
        #pragma unroll
        for (int ks = 0; ks < 2; ++ks)
            b[ks][ct] = wb[(ct * 2 + ks) * 64];

    uint4 ah[2][2], al[2][2];
    #pragma unroll
    for (int rt = 0; rt < 2; ++rt) {
        int row = p0 + rt * 16 + r;
        #pragma unroll
        for (int ks = 0; ks < 2; ++ks) {
            float v[8];
            if (row < N) {
                float4 v0 = *(const float4*)(A + (size_t)row * 64 + ks * 32 + lq * 8);
                float4 v1 = *(const float4*)(A + (size_t)row * 64 + ks * 32 + lq * 8 + 4);
                v[0]=v0.x; v[1]=v0.y; v[2]=v0.z; v[3]=v0.w;
                v[4]=v1.x; v[5]=v1.y; v[6]=v1.z; v[7]=v1.w;
            } else {
                #pragma unroll
                for (int j = 0; j < 8; ++j) v[j] = 0.f;
            }
            split8(v, ah[rt][ks], al[rt][ks]);
        }
    }

    f32x4 acc[2][4];
    #pragma unroll
    for (int i = 0; i < 2; ++i)
        #pragma unroll
        for (int j = 0; j < 4; ++j) acc[i][j] = (f32x4){0.f, 0.f, 0.f, 0.f};

    #pragma unroll
    for (int ks = 0; ks < 2; ++ks)
        #pragma unroll
        for (int rt = 0; rt < 2; ++rt)
            #pragma unroll
            for (int ct = 0; ct < 4; ++ct) {
                acc[rt][ct] = mfma16(ah[rt][ks], b[ks][ct], acc[rt][ct]);
                acc[rt][ct] = mfma16(al[rt][ks], b[ks][ct], acc[rt][ct]);
            }

    #pragma unroll
    for (int rt = 0; rt < 2; ++rt)
        #pragma unroll
        for (int j = 0; j < 4; ++j) {
            int row = p0 + rt * 16 + lq * 4 + j;
            if (row < N) {
                #pragma unroll
                for (int ct = 0; ct < 4; ++ct)
                    O[(size_t)row * 64 + ct * 16 + r] = acc[rt][ct][j];
            }
        }
}

// ---------------- K1: clear bitmap + counters ----------------
__global__ void clear_meta(uint4* __restrict__ bitmap4, int nwords4, int* __restrict__ cnt) {
    int i = blockIdx.x * 256 + threadIdx.x;
    if (i < nwords4) bitmap4[i] = (uint4){0, 0, 0, 0};
    if (blockIdx.x == 0 && threadIdx.x < 26) cnt[threadIdx.x * 16] = 0;
}

// ---------------- K2: scatter table/bitmap + prep W frags (mixed grid) ----------------
__global__ void __launch_bounds__(256) scatter_prep(
    const int* __restrict__ coords, int* __restrict__ table,
    unsigned* __restrict__ bitmap, int N, int scatB,
    const float* __restrict__ W1, const float* __restrict__ W2,
    f16* __restrict__ Wp1, f16* __restrict__ Wp2)
{
    const int tid = threadIdx.x;
    if (blockIdx.x < scatB) {
        int i = blockIdx.x * 256 + tid;
        if (i < N) {
            int4 c = ((const int4*)coords)[i];
            int key = ((c.x * SGRID + c.y) * SGRID + c.z) * SGRID + c.w;
            table[key] = i;
            atomicOr(&bitmap[key >> 5], 1u << (key & 31));
        }
        return;
    }
    int idx = (blockIdx.x - scatB) * 256 + tid;   // < 27648
    const int half = 27 * 512;
    const float* W = (idx < half) ? W1 : W2;
    f16* Wp = (idx < half) ? Wp1 : Wp2;
    int id = (idx < half) ? idx : idx - half;
    int lane = id & 63;
    int ks = (id >> 6) & 1;
    int ct = (id >> 7) & 3;
    int o  = id >> 9;
    int co  = ct * 16 + (lane & 15);
    int ci0 = ks * 32 + (lane >> 4) * 8;
    union { f16 h[8]; uint4 u; } hv;
    #pragma unroll
    for (int j = 0; j < 8; ++j)
        hv.h[j] = (f16)W[((size_t)o * 64 + ci0 + j) * 64 + co];
    ((uint4*)Wp)[id] = hv.u;
}

// ---------------- K3: center tap layer 1 (first) + grid-stride flat pair build ----------------
__global__ void __launch_bounds__(256) build_center(
    const int* __restrict__ coords, const int* __restrict__ table,
    const unsigned* __restrict__ bitmap,
    int* __restrict__ pin, int* __restrict__ pout, int* __restrict__ cnt,
    int N, int chunks, int centerB, int probeB,
    const float* __restrict__ F, const f16* __restrict__ Wp, float* __restrict__ H)
{
    const int tid = threadIdx.x;
    const int bid = blockIdx.x;

    if (bid < centerB) {               // BW-bound center blocks launch first
        int gw = (bid * 256 + tid) >> 6;
        if (gw < (N + 31) >> 5)
            center_body(F, Wp, H, N, gw, tid & 63);
        return;
    }

    // persistent probe blocks: grid-stride over (slot, chunk) tiles
    __shared__ int swc[4];
    const int lane = tid & 63, wave = tid >> 6;
    const int ntiles = 26 * chunks;

    for (int t = bid - centerB; t < ntiles; t += probeB) {
        const int slot  = t / chunks;
        const int chunk = t - slot * chunks;
        const int n     = chunk * 256 + tid;

        bool maybe = false;
        int qkey = 0;
        if (n < N) {
            int4 c = ((const int4*)coords)[n];
            int o = slot < 13 ? slot : slot + 1;
            int dx = o / 9 - 1, dy = (o / 3) % 3 - 1, dz = o % 3 - 1;
            int qx = c.y + dx, qy = c.z + dy, qz = c.w + dz;
            if ((unsigned)qx < SGRID && (unsigned)qy < SGRID && (unsigned)qz < SGRID) {
                qkey = ((c.x * SGRID + qx) * SGRID + qy) * SGRID + qz;
                maybe = (bitmap[qkey >> 5] >> (qkey & 31)) & 1u;
            }
        }
        // branchless guarded load: no exec-branch, masked lanes broadcast table[0]
        int v = table[maybe ? qkey : 0];
        int nb = maybe ? v : -1;

        unsigned long long bal = __ballot(nb >= 0);
        if (lane == 0) swc[wave] = (int)__popcll(bal);
        __syncthreads();
        if (tid == 0) {
            int t0 = swc[0], t1 = swc[1], t2 = swc[2], t3 = swc[3];
            int tot = t0 + t1 + t2 + t3;
            int base = tot ? atomicAdd(&cnt[slot * 16], tot) : 0;
            swc[0] = base;
            swc[1] = base + t0;
            swc[2] = base + t0 + t1;
            swc[3] = base + t0 + t1 + t2;
        }
        __syncthreads();
        if (nb >= 0) {
            int pos = swc[wave] + (int)__popcll(bal & ((1ull << lane) - 1ull));
            if (pos < CAP) {
                pin[slot * CAP + pos]  = nb;
                pout[slot * CAP + pos] = n;
            }
        }
        __syncthreads();   // swc safe before next tile's writes
    }
}

// ---------------- K5: standalone center (layer 2) ----------------
__global__ void __launch_bounds__(256) conv_center(
    const float* __restrict__ A, const f16* __restrict__ Wp,
    float* __restrict__ O, int N)
{
    int gw = (blockIdx.x * 256 + threadIdx.x) >> 6;
    if (gw < (N + 31) >> 5)
        center_body(A, Wp, O, N, gw, threadIdx.x & 63);
}

// ---------------- K4/K6: sparse taps, 16-pair chunks, cout halves ----------------
__global__ void __launch_bounds__(256) conv_sparse(
    const float* __restrict__ A, const f16* __restrict__ Wp,
    const int* __restrict__ pin, const int* __restrict__ pout,
    const int* __restrict__ cnt, float* __restrict__ O)
{
    int w = (blockIdx.x * 256 + threadIdx.x) >> 6;
    if (w >= 26 * 512) return;
    int slot  = w >> 9;                  // 256 chunks x 2 ch-halves per slot
    int rem   = w & 511;
    int chunk = rem >> 1;
    int ch    = rem & 1;
    int cn = cnt[slot * 16]; if (cn > CAP) cn = CAP;
    int i0 = chunk * 16;
    if (i0 >= cn) return;
    int o = slot < 13 ? slot : slot + 1;
    const int lane = threadIdx.x & 63, r = lane & 15, lq = lane >> 4;

    const uint4* wb = (const uint4*)Wp + (size_t)o * 512 + lane;
    uint4 b[2][2];   // [ct][ks], couts (ch*2+ct)*16..
    #pragma unroll
    for (int ct = 0; ct < 2; ++ct)
        #pragma unroll
        for (int ks = 0; ks < 2; ++ks)
            b[ct][ks] = wb[((ch * 2 + ct) * 2 + ks) * 64];

    int p = i0 + r;
    int in = (p < cn) ? pin[slot * CAP + p] : -1;
    uint4 ah[2], al[2];
    #pragma unroll
    for (int ks = 0; ks < 2; ++ks) {
        float v[8];
        if (in >= 0) {
            float4 v0 = *(const float4*)(A + (size_t)in * 64 + ks * 32 + lq * 8);
            float4 v1 = *(const float4*)(A + (size_t)in * 64 + ks * 32 + lq * 8 + 4);
            v[0]=v0.x; v[1]=v0.y; v[2]=v0.z; v[3]=v0.w;
            v[4]=v1.x; v[5]=v1.y; v[6]=v1.z; v[7]=v1.w;
        } else {
            #pragma unroll
            for (int j = 0; j < 8; ++j) v[j] = 0.f;
        }
        split8(v, ah[ks], al[ks]);
    }

    f32x4 acc[2];
    acc[0] = (f32x4){0.f, 0.f, 0.f, 0.f};
    acc[1] = (f32x4){0.f, 0.f, 0.f, 0.f};
    #pragma unroll
    for (int ks = 0; ks < 2; ++ks)
        #pragma unroll
        for (int ct = 0; ct < 2; ++ct) {
            acc[ct] = mfma16(ah[ks], b[ct][ks], acc[ct]);
            acc[ct] = mfma16(al[ks], b[ct][ks], acc[ct]);
        }

    #pragma unroll
    for (int j = 0; j < 4; ++j) {
        int pr = i0 + lq * 4 + j;
        if (pr < cn) {
            int oidx = pout[slot * CAP + pr];
            #pragma unroll
            for (int ct = 0; ct < 2; ++ct)
                atomicAdd(&O[(size_t)oidx * 64 + (ch * 2 + ct) * 16 + r], acc[ct][j]);
        }
    }
}

extern "C" void kernel_launch(void* const* d_in, const int* in_sizes, int n_in,
                              void* d_out, int out_size, void* d_ws, size_t ws_size,
                              hipStream_t stream) {
    const float* feats  = (const float*)d_in[0];
    const int*   coords = (const int*)d_in[1];
    const float* W1     = (const float*)d_in[2];
    const float* W2     = (const float*)d_in[3];
    float* out = (float*)d_out;

    const int N = in_sizes[0] / 64;
    const size_t nvox = 2ull * SGRID * SGRID * SGRID;   // B * S^3

    char* p = (char*)d_ws;
    int*      table  = (int*)p;      p += nvox * 4;          // no init needed (bitmap-guarded)
    unsigned* bitmap = (unsigned*)p; p += (nvox / 32) * 4;   // 524 KB
    int*      cnt    = (int*)p;      p += 26 * 16 * 4;       // padded, one per cacheline
    int*      pin    = (int*)p;      p += 26ull * CAP * 4;
    int*      pout   = (int*)p;      p += 26ull * CAP * 4;
    float*    H      = (float*)p;    p += (size_t)N * 64 * 4;
    f16*      Wp1    = (f16*)p;      p += 27ull * 4096 * 2;
    f16*      Wp2    = (f16*)p;      p += 27ull * 4096 * 2;

    const int bm4     = (int)(nvox / 32 / 4);            // 32768
    const int scatB   = (N + 255) / 256;                 // 391
    const int chunks  = scatB;                           // probe chunks per slot
    const int ngroups = (N + 31) / 32;
    const int centerB = (ngroups + 3) / 4;               // 1 wave per group, 4/block
    const int probeB  = 1536;                            // persistent probe blocks
    const int sparseB = 26 * 512 / 4;                    // 3328 blocks

    clear_meta<<<(bm4 + 255) / 256, 256, 0, stream>>>((uint4*)bitmap, bm4, cnt);
    scatter_prep<<<scatB + 108, 256, 0, stream>>>(coords, table, bitmap, N, scatB,
                                                  W1, W2, Wp1, Wp2);
    build_center<<<centerB + probeB, 256, 0, stream>>>(coords, table, bitmap,
                                                       pin, pout, cnt, N, chunks,
                                                       centerB, probeB,
                                                       feats, Wp1, H);
    conv_sparse<<<sparseB, 256, 0, stream>>>(feats, Wp1, pin, pout, cnt, H);
    conv_center<<<centerB, 256, 0, stream>>>(H, Wp2, out, N);
    conv_sparse<<<sparseB, 256, 0, stream>>>(H, Wp2, pin, pout, cnt, out);
}

// Round 11
// 91.428 us; speedup vs baseline: 1.2136x; 1.1191x over previous
//
#include <hip/hip_runtime.h>
#include <stdint.h>

#define SGRID 128
#define CAP 4096   // per-offset pair capacity (expect ~2400 at this density)

typedef _Float16 f16;
typedef f16 f16x8 __attribute__((ext_vector_type(8)));
typedef float f32x4 __attribute__((ext_vector_type(4)));

static __device__ __forceinline__ f32x4 mfma16(uint4 a, uint4 b, f32x4 c) {
    union { uint4 u; f16x8 v; } ua, ub;
    ua.u = a; ub.u = b;
    return __builtin_amdgcn_mfma_f32_16x16x32_f16(ua.v, ub.v, c, 0, 0, 0);
}

// split 8 f32 -> f16 hi + f16 lo (packed uint4 fragments)
static __device__ __forceinline__ void split8(const float* v, uint4& hu, uint4& lu) {
    union { f16 h[8]; uint4 u; } hv, lv;
    #pragma unroll
    for (int j = 0; j < 8; ++j) {
        f16 h = (f16)v[j];
        hv.h[j] = h;
        lv.h[j] = (f16)(v[j] - (float)h);
    }
    hu = hv.u; lu = lv.u;
}

// ---- shared center-tap body: one wave = 32 points x 64 cout, W slot 13 ----
static __device__ __forceinline__ void center_body(
    const float* __restrict__ A, const f16* __restrict__ Wp,
    float* __restrict__ O, int N, int gw, int lane)
{
    const int r = lane & 15, lq = lane >> 4;
    const int p0 = gw * 32;

    const uint4* wb = (const uint4*)Wp + 13 * 512 + lane;
    uint4 b[2][4];
    #pragma unroll
    for (int ct = 0; ct < 4; ++ct)
        #pragma unroll
        for (int ks = 0; ks < 2; ++ks)
            b[ks][ct] = wb[(ct * 2 + ks) * 64];

    uint4 ah[2][2], al[2][2];
    #pragma unroll
    for (int rt = 0; rt < 2; ++rt) {
        int row = p0 + rt * 16 + r;
        #pragma unroll
        for (int ks = 0; ks < 2; ++ks) {
            float v[8];
            if (row < N) {
                float4 v0 = *(const float4*)(A + (size_t)row * 64 + ks * 32 + lq * 8);
                float4 v1 = *(const float4*)(A + (size_t)row * 64 + ks * 32 + lq * 8 + 4);
                v[0]=v0.x; v[1]=v0.y; v[2]=v0.z; v[3]=v0.w;
                v[4]=v1.x; v[5]=v1.y; v[6]=v1.z; v[7]=v1.w;
            } else {
                #pragma unroll
                for (int j = 0; j < 8; ++j) v[j] = 0.f;
            }
            split8(v, ah[rt][ks], al[rt][ks]);
        }
    }

    f32x4 acc[2][4];
    #pragma unroll
    for (int i = 0; i < 2; ++i)
        #pragma unroll
        for (int j = 0; j < 4; ++j) acc[i][j] = (f32x4){0.f, 0.f, 0.f, 0.f};

    #pragma unroll
    for (int ks = 0; ks < 2; ++ks)
        #pragma unroll
        for (int rt = 0; rt < 2; ++rt)
            #pragma unroll
            for (int ct = 0; ct < 4; ++ct) {
                acc[rt][ct] = mfma16(ah[rt][ks], b[ks][ct], acc[rt][ct]);
                acc[rt][ct] = mfma16(al[rt][ks], b[ks][ct], acc[rt][ct]);
            }

    #pragma unroll
    for (int rt = 0; rt < 2; ++rt)
        #pragma unroll
        for (int j = 0; j < 4; ++j) {
            int row = p0 + rt * 16 + lq * 4 + j;
            if (row < N) {
                #pragma unroll
                for (int ct = 0; ct < 4; ++ct)
                    O[(size_t)row * 64 + ct * 16 + r] = acc[rt][ct][j];
            }
        }
}

// ---------------- K1: clear bitmap + counters ----------------
__global__ void clear_meta(uint4* __restrict__ bitmap4, int nwords4, int* __restrict__ cnt) {
    int i = blockIdx.x * 256 + threadIdx.x;
    if (i < nwords4) bitmap4[i] = (uint4){0, 0, 0, 0};
    if (blockIdx.x == 0 && threadIdx.x < 26) cnt[threadIdx.x * 16] = 0;
}

// ---------------- K2: scatter table/bitmap + prep W frags (mixed grid) ----------------
__global__ void __launch_bounds__(256) scatter_prep(
    const int* __restrict__ coords, int* __restrict__ table,
    unsigned* __restrict__ bitmap, int N, int scatB,
    const float* __restrict__ W1, const float* __restrict__ W2,
    f16* __restrict__ Wp1, f16* __restrict__ Wp2)
{
    const int tid = threadIdx.x;
    if (blockIdx.x < scatB) {
        int i = blockIdx.x * 256 + tid;
        if (i < N) {
            int4 c = ((const int4*)coords)[i];
            int key = ((c.x * SGRID + c.y) * SGRID + c.z) * SGRID + c.w;
            table[key] = i;
            atomicOr(&bitmap[key >> 5], 1u << (key & 31));
        }
        return;
    }
    int idx = (blockIdx.x - scatB) * 256 + tid;   // < 27648
    const int half = 27 * 512;
    const float* W = (idx < half) ? W1 : W2;
    f16* Wp = (idx < half) ? Wp1 : Wp2;
    int id = (idx < half) ? idx : idx - half;
    int lane = id & 63;
    int ks = (id >> 6) & 1;
    int ct = (id >> 7) & 3;
    int o  = id >> 9;
    int co  = ct * 16 + (lane & 15);
    int ci0 = ks * 32 + (lane >> 4) * 8;
    union { f16 h[8]; uint4 u; } hv;
    #pragma unroll
    for (int j = 0; j < 8; ++j)
        hv.h[j] = (f16)W[((size_t)o * 64 + ci0 + j) * 64 + co];
    ((uint4*)Wp)[id] = hv.u;
}

// ---------------- K3: 9-column trio probe + pair build (probe blocks FIRST) + center1 ----
__global__ void __launch_bounds__(256) build_center(
    const int* __restrict__ coords, const int* __restrict__ table,
    const unsigned* __restrict__ bitmap,
    int* __restrict__ pin, int* __restrict__ pout, int* __restrict__ cnt,
    int N, int probeChunks,
    const float* __restrict__ F, const f16* __restrict__ Wp, float* __restrict__ H)
{
    const int tid = threadIdx.x;
    const int bid = blockIdx.x;

    if (bid >= probeChunks) {            // center-tap blocks fill in behind the probes
        int gw = ((bid - probeChunks) * 256 + tid) >> 6;
        if (gw < (N + 31) >> 5)
            center_body(F, Wp, H, N, gw, tid & 63);
        return;
    }

    // ---- one point per thread: 9 bitmap-column loads give all 26 occupancy bits ----
    __shared__ unsigned long long sbal[26][4];
    __shared__ int sbase[26];
    const int lane = tid & 63, wave = tid >> 6;
    const int n = bid * 256 + tid;
    const bool valid = n < N;

    int4 c = {0, 0, 0, 0};
    if (valid) c = ((const int4*)coords)[n];
    const int z = c.w, bz = z & 31;
    const int keyhi = (c.x * SGRID + c.y) * SGRID + c.z;

    unsigned trio[9];   // bit0 = z-1 occ, bit1 = z, bit2 = z+1
    #pragma unroll
    for (int cidx = 0; cidx < 9; ++cidx) {
        int dx = cidx / 3 - 1, dy = cidx % 3 - 1;
        int qx = c.y + dx, qy = c.z + dy;
        bool colok = valid && ((unsigned)qx < SGRID) && ((unsigned)qy < SGRID);
        int colhi = (c.x * SGRID + qx) * SGRID + qy;
        int iw = (colhi << 2) + (z >> 5);
        unsigned w0 = colok ? bitmap[iw] : 0u;
        unsigned t;
        if (bz == 0) {
            unsigned wm = (colok && z > 0) ? bitmap[iw - 1] : 0u;
            t = ((w0 << 1) | (wm >> 31)) & 7u;
        } else if (bz == 31) {
            unsigned wp = (colok && z < SGRID - 1) ? bitmap[iw + 1] : 0u;
            t = ((w0 >> 30) | (wp << 2)) & 7u;
        } else {
            t = (w0 >> (bz - 1)) & 7u;
        }
        if (z == 0) t &= ~1u;
        if (z == SGRID - 1) t &= ~4u;
        trio[cidx] = t;
    }

    // ---- table loads only for occupied slots (branchless; dummies broadcast line 0) ----
    const int key = keyhi * SGRID + z;
    int nb[26];
    #pragma unroll
    for (int s = 0; s < 26; ++s) {
        int o = s < 13 ? s : s + 1;
        int cidx = (o / 9) * 3 + (o / 3) % 3;
        int dzb = o % 3;                                  // bit index (dz+1)
        bool occ = (trio[cidx] >> dzb) & 1u;
        int qkey = key + ((o / 9 - 1) * SGRID * SGRID + ((o / 3) % 3 - 1) * SGRID + (dzb - 1));
        int v = table[occ ? qkey : 0];
        nb[s] = occ ? v : -1;
    }

    // ---- ballots -> LDS ----
    #pragma unroll
    for (int s = 0; s < 26; ++s) {
        unsigned long long bal = __ballot(nb[s] >= 0);
        if (lane == 0) sbal[s][wave] = bal;
    }
    __syncthreads();

    // ---- 26 parallel atomics (one lane per slot) ----
    if (tid < 26) {
        int tot = (int)__popcll(sbal[tid][0]) + (int)__popcll(sbal[tid][1])
                + (int)__popcll(sbal[tid][2]) + (int)__popcll(sbal[tid][3]);
        int base = 0;
        if (tot) base = atomicAdd(&cnt[tid * 16], tot);
        sbase[tid] = base;
    }
    __syncthreads();

    // ---- emit pairs at deterministic in-block ranks ----
    #pragma unroll
    for (int s = 0; s < 26; ++s) {
        if (nb[s] >= 0) {
            unsigned long long bal = sbal[s][wave];
            int rank = (int)__popcll(bal & ((1ull << lane) - 1ull));
            #pragma unroll
            for (int w = 0; w < 4; ++w)
                if (w < wave) rank += (int)__popcll(sbal[s][w]);
            int pos = sbase[s] + rank;
            if (pos < CAP) {
                pin[s * CAP + pos]  = nb[s];
                pout[s * CAP + pos] = n;
            }
        }
    }
}

// ---------------- K5: standalone center (layer 2) ----------------
__global__ void __launch_bounds__(256) conv_center(
    const float* __restrict__ A, const f16* __restrict__ Wp,
    float* __restrict__ O, int N)
{
    int gw = (blockIdx.x * 256 + threadIdx.x) >> 6;
    if (gw < (N + 31) >> 5)
        center_body(A, Wp, O, N, gw, threadIdx.x & 63);
}

// ---------------- K4/K6: sparse taps, 16-pair chunks, cout halves ----------------
__global__ void __launch_bounds__(256) conv_sparse(
    const float* __restrict__ A, const f16* __restrict__ Wp,
    const int* __restrict__ pin, const int* __restrict__ pout,
    const int* __restrict__ cnt, float* __restrict__ O)
{
    int w = (blockIdx.x * 256 + threadIdx.x) >> 6;
    if (w >= 26 * 512) return;
    int slot  = w >> 9;                  // 256 chunks x 2 ch-halves per slot
    int rem   = w & 511;
    int chunk = rem >> 1;
    int ch    = rem & 1;
    int cn = cnt[slot * 16]; if (cn > CAP) cn = CAP;
    int i0 = chunk * 16;
    if (i0 >= cn) return;
    int o = slot < 13 ? slot : slot + 1;
    const int lane = threadIdx.x & 63, r = lane & 15, lq = lane >> 4;

    const uint4* wb = (const uint4*)Wp + (size_t)o * 512 + lane;
    uint4 b[2][2];   // [ct][ks], couts (ch*2+ct)*16..
    #pragma unroll
    for (int ct = 0; ct < 2; ++ct)
        #pragma unroll
        for (int ks = 0; ks < 2; ++ks)
            b[ct][ks] = wb[((ch * 2 + ct) * 2 + ks) * 64];

    int p = i0 + r;
    int in = (p < cn) ? pin[slot * CAP + p] : -1;
    uint4 ah[2], al[2];
    #pragma unroll
    for (int ks = 0; ks < 2; ++ks) {
        float v[8];
        if (in >= 0) {
            float4 v0 = *(const float4*)(A + (size_t)in * 64 + ks * 32 + lq * 8);
            float4 v1 = *(const float4*)(A + (size_t)in * 64 + ks * 32 + lq * 8 + 4);
            v[0]=v0.x; v[1]=v0.y; v[2]=v0.z; v[3]=v0.w;
            v[4]=v1.x; v[5]=v1.y; v[6]=v1.z; v[7]=v1.w;
        } else {
            #pragma unroll
            for (int j = 0; j < 8; ++j) v[j] = 0.f;
        }
        split8(v, ah[ks], al[ks]);
    }

    f32x4 acc[2];
    acc[0] = (f32x4){0.f, 0.f, 0.f, 0.f};
    acc[1] = (f32x4){0.f, 0.f, 0.f, 0.f};
    #pragma unroll
    for (int ks = 0; ks < 2; ++ks)
        #pragma unroll
        for (int ct = 0; ct < 2; ++ct) {
            acc[ct] = mfma16(ah[ks], b[ct][ks], acc[ct]);
            acc[ct] = mfma16(al[ks], b[ct][ks], acc[ct]);
        }

    #pragma unroll
    for (int j = 0; j < 4; ++j) {
        int pr = i0 + lq * 4 + j;
        if (pr < cn) {
            int oidx = pout[slot * CAP + pr];
            #pragma unroll
            for (int ct = 0; ct < 2; ++ct)
                atomicAdd(&O[(size_t)oidx * 64 + (ch * 2 + ct) * 16 + r], acc[ct][j]);
        }
    }
}

extern "C" void kernel_launch(void* const* d_in, const int* in_sizes, int n_in,
                              void* d_out, int out_size, void* d_ws, size_t ws_size,
                              hipStream_t stream) {
    const float* feats  = (const float*)d_in[0];
    const int*   coords = (const int*)d_in[1];
    const float* W1     = (const float*)d_in[2];
    const float* W2     = (const float*)d_in[3];
    float* out = (float*)d_out;

    const int N = in_sizes[0] / 64;
    const size_t nvox = 2ull * SGRID * SGRID * SGRID;   // B * S^3

    char* p = (char*)d_ws;
    int*      table  = (int*)p;      p += nvox * 4;          // no init needed (bitmap-guarded)
    unsigned* bitmap = (unsigned*)p; p += (nvox / 32) * 4;   // 524 KB
    int*      cnt    = (int*)p;      p += 26 * 16 * 4;       // padded, one per cacheline
    int*      pin    = (int*)p;      p += 26ull * CAP * 4;
    int*      pout   = (int*)p;      p += 26ull * CAP * 4;
    float*    H      = (float*)p;    p += (size_t)N * 64 * 4;
    f16*      Wp1    = (f16*)p;      p += 27ull * 4096 * 2;
    f16*      Wp2    = (f16*)p;      p += 27ull * 4096 * 2;

    const int bm4     = (int)(nvox / 32 / 4);            // 32768
    const int scatB   = (N + 255) / 256;                 // 391
    const int ngroups = (N + 31) / 32;
    const int centerB = (ngroups + 3) / 4;               // 1 wave per group, 4/block
    const int sparseB = 26 * 512 / 4;                    // 3328 blocks

    clear_meta<<<(bm4 + 255) / 256, 256, 0, stream>>>((uint4*)bitmap, bm4, cnt);
    scatter_prep<<<scatB + 108, 256, 0, stream>>>(coords, table, bitmap, N, scatB,
                                                  W1, W2, Wp1, Wp2);
    build_center<<<scatB + centerB, 256, 0, stream>>>(coords, table, bitmap,
                                                      pin, pout, cnt, N, scatB,
                                                      feats, Wp1, H);
    conv_sparse<<<sparseB, 256, 0, stream>>>(feats, Wp1, pin, pout, cnt, H);
    conv_center<<<centerB, 256, 0, stream>>>(H, Wp2, out, N);
    conv_sparse<<<sparseB, 256, 0, stream>>>(H, Wp2, pin, pout, cnt, out);
}